// Round 13
// baseline (378.534 us; speedup 1.0000x reference)
//
#include <hip/hip_runtime.h>

#define S_LEN 2048
#define D_MODEL 2048
#define NH 16
#define HD 128

typedef __attribute__((ext_vector_type(4))) float f32x4;
typedef __attribute__((ext_vector_type(8))) short short8;
typedef __attribute__((ext_vector_type(4))) short s16x4;
typedef __attribute__((ext_vector_type(8))) __bf16 bf16x8;
typedef __attribute__((ext_vector_type(4))) unsigned short us4;

__device__ __forceinline__ unsigned short f2bf(float f) {
  unsigned int u = __builtin_bit_cast(unsigned int, f);
  return (unsigned short)((u + 0x7fffu + ((u >> 16) & 1u)) >> 16);
}

__device__ __forceinline__ f32x4 mfma_bf16(short8 a, short8 b, f32x4 c) {
  return __builtin_amdgcn_mfma_f32_16x16x32_bf16(
      __builtin_bit_cast(bf16x8, a), __builtin_bit_cast(bf16x8, b), c, 0, 0, 0);
}

// 16x16x16 bf16 MFMA (A,B = 4 bf16 each). Builtin if present, else inline asm.
__device__ __forceinline__ f32x4 mfma16_bf16(s16x4 a, s16x4 b, f32x4 c) {
#if __has_builtin(__builtin_amdgcn_mfma_f32_16x16x16bf16_1k)
  return __builtin_amdgcn_mfma_f32_16x16x16bf16_1k(a, b, c, 0, 0, 0);
#else
  asm("v_mfma_f32_16x16x16_bf16 %0, %1, %2, %0" : "+v"(c) : "v"(a), "v"(b));
  return c;
#endif
}

__device__ __forceinline__ void gload16(const unsigned short* g, unsigned short* l) {
  __builtin_amdgcn_global_load_lds(
      (const __attribute__((address_space(1))) void*)g,
      (__attribute__((address_space(3))) void*)l, 16, 0, 0);
}

// ---------------- cast x (f32 -> bf16), both batches in one dispatch ----------------
__global__ void cast_bf16_2(const float* __restrict__ src, unsigned short* __restrict__ dst0,
                            unsigned short* __restrict__ dst1) {
  int i = blockIdx.x * blockDim.x + threadIdx.x;
  float4 v = ((const float4*)src)[i];
  us4 o = { f2bf(v.x), f2bf(v.y), f2bf(v.z), f2bf(v.w) };
  if (i < 1048576) ((us4*)dst0)[i] = o;
  else             ((us4*)dst1)[i - 1048576] = o;
}

// ---------------- transpose-cast weights ----------------
__global__ void transpose_cast3(const float* __restrict__ Wq, const float* __restrict__ Wk,
                                const float* __restrict__ Wv, unsigned short* __restrict__ Wt) {
  __shared__ unsigned short tile[32][33];
  const float* W = (blockIdx.z == 0) ? Wq : (blockIdx.z == 1) ? Wk : Wv;
  unsigned short* dst = Wt + (size_t)blockIdx.z * 4194304;
  int bx = blockIdx.x * 32, by = blockIdx.y * 32;
  int tx = threadIdx.x, ty = threadIdx.y;
#pragma unroll
  for (int i = 0; i < 32; i += 8)
    tile[ty + i][tx] = f2bf(W[(by + ty + i) * D_MODEL + bx + tx]);
  __syncthreads();
#pragma unroll
  for (int i = 0; i < 32; i += 8)
    dst[(bx + ty + i) * D_MODEL + by + tx] = tile[tx][ty + i];
}

__global__ void transpose_cast(const float* __restrict__ W, unsigned short* __restrict__ Wt) {
  __shared__ unsigned short tile[32][33];
  int bx = blockIdx.x * 32, by = blockIdx.y * 32;
  int tx = threadIdx.x, ty = threadIdx.y;
#pragma unroll
  for (int i = 0; i < 32; i += 8)
    tile[ty + i][tx] = f2bf(W[(by + ty + i) * D_MODEL + bx + tx]);
  __syncthreads();
#pragma unroll
  for (int i = 0; i < 32; i += 8)
    Wt[(bx + ty + i) * D_MODEL + by + tx] = tile[tx][ty + i];
}

// ================= 128x128 GEMM K-loop (r9 structure) =================
#define GEMM_KLOOP(Ag0, Ag1, Bg0, Bg1, acc, t, fu, wr, wc, lr)           \
  __shared__ unsigned short lA[3][128 * 32];                             \
  __shared__ unsigned short lB[3][128 * 32];                             \
  do {                                                                   \
    const int nt = D_MODEL >> 5;                                         \
    _Pragma("unroll") for (int i = 0; i < 2; i++) {                      \
      const int _k = i * 32;                                             \
      gload16(Ag0 + _k, lA[i] + t * 8);                                  \
      gload16(Ag1 + _k, lA[i] + 2048 + t * 8);                           \
      gload16(Bg0 + _k, lB[i] + t * 8);                                  \
      gload16(Bg1 + _k, lB[i] + 2048 + t * 8);                           \
    }                                                                    \
    int cur = 0;                                                         \
    for (int tk = 0; tk < nt; ++tk) {                                    \
      if (tk + 1 < nt) {                                                 \
        asm volatile("s_waitcnt vmcnt(4)" ::: "memory");                 \
      } else {                                                           \
        asm volatile("s_waitcnt vmcnt(0)" ::: "memory");                 \
      }                                                                  \
      __builtin_amdgcn_sched_barrier(0);                                 \
      __builtin_amdgcn_s_barrier();                                      \
      __builtin_amdgcn_sched_barrier(0);                                 \
      if (tk + 2 < nt) {                                                 \
        int nx2 = cur + 2;                                               \
        if (nx2 >= 3) nx2 -= 3;                                          \
        const int _k = (tk + 2) * 32;                                    \
        gload16(Ag0 + _k, lA[nx2] + t * 8);                              \
        gload16(Ag1 + _k, lA[nx2] + 2048 + t * 8);                       \
        gload16(Bg0 + _k, lB[nx2] + t * 8);                              \
        gload16(Bg1 + _k, lB[nx2] + 2048 + t * 8);                       \
      }                                                                  \
      const unsigned short* a = lA[cur];                                 \
      const unsigned short* b = lB[cur];                                 \
      short8 af[4], bf[4];                                               \
      _Pragma("unroll") for (int mi = 0; mi < 4; mi++)                   \
        af[mi] = *(const short8*)&a[(wr * 64 + mi * 16 + lr) * 32 + fu]; \
      _Pragma("unroll") for (int ni = 0; ni < 4; ni++)                   \
        bf[ni] = *(const short8*)&b[(wc * 64 + ni * 16 + lr) * 32 + fu]; \
      __builtin_amdgcn_s_setprio(1);                                     \
      _Pragma("unroll") for (int mi = 0; mi < 4; mi++)                   \
        _Pragma("unroll") for (int ni = 0; ni < 4; ni++)                 \
          acc[mi][ni] = mfma_bf16(af[mi], bf[ni], acc[mi][ni]);          \
      __builtin_amdgcn_s_setprio(0);                                     \
      cur = (cur == 2) ? 0 : cur + 1;                                    \
    }                                                                    \
  } while (0)

// ---------------- fused QKV GEMM: [2048,2048] @ [6144,2048]^T ----------------
__global__ __launch_bounds__(256, 2) void gemm_qkv(
    const unsigned short* __restrict__ A, const unsigned short* __restrict__ Bt,
    unsigned short* __restrict__ qb, unsigned short* __restrict__ kb,
    unsigned short* __restrict__ vtb) {
  const int t = threadIdx.x;
  const int l = t & 63, w = t >> 6;
  const int wr = w >> 1, wc = w & 1;
  const int lr = l & 15, lk = l >> 4;
  const int n0 = blockIdx.x * 128, m0 = blockIdx.y * 128;

  const int arow = t >> 2;
  const int au = ((t & 3) ^ ((arow >> 1) & 3)) * 8;
  const unsigned short* Ag0 = A + (size_t)(m0 + arow) * D_MODEL + au;
  const unsigned short* Ag1 = Ag0 + 64 * D_MODEL;
  const unsigned short* Bg0 = Bt + (size_t)(n0 + arow) * D_MODEL + au;
  const unsigned short* Bg1 = Bg0 + 64 * D_MODEL;
  const int fu = (lk ^ ((lr >> 1) & 3)) * 8;

  f32x4 acc[4][4] = {};
  GEMM_KLOOP(Ag0, Ag1, Bg0, Bg1, acc, t, fu, wr, wc, lr);

  if (n0 < 4096) {
    unsigned short* C = (n0 < 2048) ? qb : kb;
    const int nbase = n0 & 2047;
#pragma unroll
    for (int mi = 0; mi < 4; mi++) {
      int r0 = m0 + wr * 64 + mi * 16 + lk * 4;
#pragma unroll
      for (int ni = 0; ni < 4; ni++) {
        int c2 = nbase + wc * 64 + ni * 16 + lr;
#pragma unroll
        for (int r = 0; r < 4; r++)
          C[(size_t)(r0 + r) * D_MODEL + c2] = f2bf(acc[mi][ni][r]);
      }
    }
  } else {
    const int nb = n0 - 4096;
#pragma unroll
    for (int mi = 0; mi < 4; mi++) {
      int s = m0 + wr * 64 + mi * 16 + lk * 4;
#pragma unroll
      for (int ni = 0; ni < 4; ni++) {
        int n = nb + wc * 64 + ni * 16 + lr;
        int h = n >> 7, d = n & (HD - 1);
        us4 pk = { f2bf(acc[mi][ni][0]), f2bf(acc[mi][ni][1]),
                   f2bf(acc[mi][ni][2]), f2bf(acc[mi][ni][3]) };
        *(us4*)&vtb[((size_t)(h * HD + d)) * S_LEN + s] = pk;
      }
    }
  }
}

// ---------------- combined output GEMM: [4096,2048] @ [2048,2048]^T + bias ----------------
__global__ __launch_bounds__(256, 2) void gemm_out(
    const unsigned short* __restrict__ ctx0, const unsigned short* __restrict__ ctx1,
    const unsigned short* __restrict__ Bt, const float* __restrict__ bias,
    float* __restrict__ out) {
  const int t = threadIdx.x;
  const int l = t & 63, w = t >> 6;
  const int wr = w >> 1, wc = w & 1;
  const int lr = l & 15, lk = l >> 4;
  const int n0 = blockIdx.x * 128, m0 = blockIdx.y * 128;

  const unsigned short* Ablk = (m0 < 2048)
      ? ctx0 + (size_t)m0 * D_MODEL
      : ctx1 + (size_t)(m0 - 2048) * D_MODEL;

  const int arow = t >> 2;
  const int au = ((t & 3) ^ ((arow >> 1) & 3)) * 8;
  const unsigned short* Ag0 = Ablk + (size_t)arow * D_MODEL + au;
  const unsigned short* Ag1 = Ag0 + 64 * D_MODEL;
  const unsigned short* Bg0 = Bt + (size_t)(n0 + arow) * D_MODEL + au;
  const unsigned short* Bg1 = Bg0 + 64 * D_MODEL;
  const int fu = (lk ^ ((lr >> 1) & 3)) * 8;

  f32x4 acc[4][4] = {};
  GEMM_KLOOP(Ag0, Ag1, Bg0, Bg1, acc, t, fu, wr, wc, lr);

#pragma unroll
  for (int mi = 0; mi < 4; mi++) {
    int r0 = m0 + wr * 64 + mi * 16 + lk * 4;
#pragma unroll
    for (int ni = 0; ni < 4; ni++) {
      int c2 = n0 + wc * 64 + ni * 16 + lr;
      float bv = bias[c2];
#pragma unroll
      for (int r = 0; r < 4; r++)
        out[(size_t)(r0 + r) * D_MODEL + c2] = acc[mi][ni][r] + bv;
    }
  }
}

// ---------------- flash attention (causal): barrier-free, LDS-free main loop ----------------
// r13: fixed-base softmax makes O and l purely additive over k -> waves split KV, not Q.
// Wave (wq,wk): q rows [qt*64+wq*32, +32), KV 16-row tiles tk=wk, wk+2, ... .
// K read global->VGPR (b128), V^T global->VGPR (b64); K/V L2-resident by h=id&15
// (2 heads/XCD). Swapped-QK score frag (k=lk*4+r, q=lr) IS the B-frag of
// v_mfma_f32_16x16x16_bf16, so P feeds PV straight from registers; V^T rows are
// its A-frag. Zero barriers / zero LDS in the loop; one LDS O/l combine at end.
__global__ __launch_bounds__(256, 2) void attn_kernel(
    const unsigned short* __restrict__ Q, const unsigned short* __restrict__ K,
    const unsigned short* __restrict__ Vt, unsigned short* __restrict__ ctx) {
  __shared__ float eO[2][16][64][4];  // 32 KB: [wq][qc*8+dt][lane][4]
  __shared__ float eL[2][2][16];      // l partials

  const int id = blockIdx.x;
  const int h = id & 15;
  const int qtl = id >> 4;
  const int qt = (qtl < 16) ? (2 * qtl) : (63 - 2 * qtl);  // pairing: qt sums to 31

  const int t = threadIdx.x, l = t & 63, w = t >> 6;
  const int wq = w >> 1, wk = w & 1;
  const int lr = l & 15, lk = l >> 4;
  const int qgb = qt * 64 + wq * 32;

  // Q fragments (B-operand of 16x16x32), pre-scaled by softmax_scale*log2(e)
  const float qscale = 0.08838834764831845f * 1.44269504088896340f;
  short8 Qf[2][4];
#pragma unroll
  for (int qc = 0; qc < 2; qc++)
#pragma unroll
    for (int kk = 0; kk < 4; kk++) {
      short8 qv = *(const short8*)&Q[(size_t)(qgb + qc * 16 + lr) * D_MODEL + h * HD + kk * 32 + lk * 8];
#pragma unroll
      for (int e = 0; e < 8; e++) {
        unsigned int u = ((unsigned int)(unsigned short)qv[e]) << 16;
        float f = __builtin_bit_cast(float, u) * qscale;
        qv[e] = (short)f2bf(f);
      }
      Qf[qc][kk] = qv;
    }

  const unsigned short* kbase = K + h * HD;               // + s*D_MODEL + d
  const unsigned short* vbase = Vt + (size_t)h * HD * S_LEN;  // + d*S_LEN + s

  const int nkv16 = qt * 4 + 2 + 2 * wq;       // 16-row tiles this wq needs
  const int nt = (nkv16 - wk + 1) >> 1;        // tiles for this (wq,wk) wave

  f32x4 O0[8] = {}, O1[8] = {};
  float ls0 = 0.f, ls1 = 0.f;
  short8 KA[4], KB[4];
  s16x4 VA[8], VB[8];

#define LOADKV(KX, VX, j_)                                                          \
  do {                                                                              \
    const int kv0_ = (wk + 2 * (j_)) * 16;                                          \
    _Pragma("unroll") for (int kk = 0; kk < 4; kk++)                                \
      KX[kk] = *(const short8*)&kbase[(size_t)(kv0_ + lr) * D_MODEL + kk * 32 + lk * 8]; \
    _Pragma("unroll") for (int dt = 0; dt < 8; dt++)                                \
      VX[dt] = *(const s16x4*)&vbase[(size_t)(dt * 16 + lr) * S_LEN + kv0_ + lk * 4];    \
  } while (0)

#define COMPUTE(KX, VX, j_)                                                         \
  do {                                                                              \
    const int kv0_ = (wk + 2 * (j_)) * 16;                                          \
    f32x4 sc0 = {}, sc1 = {};                                                       \
    _Pragma("unroll") for (int kk = 0; kk < 4; kk++) {                              \
      sc0 = mfma_bf16(KX[kk], Qf[0][kk], sc0);                                      \
      sc1 = mfma_bf16(KX[kk], Qf[1][kk], sc1);                                      \
    }                                                                               \
    if (kv0_ + 15 > qgb) {                                                          \
      _Pragma("unroll") for (int r = 0; r < 4; r++) {                               \
        const int kg = kv0_ + lk * 4 + r;                                           \
        if (kg > qgb + lr) sc0[r] = -1e30f;                                         \
        if (kg > qgb + 16 + lr) sc1[r] = -1e30f;                                    \
      }                                                                             \
    }                                                                               \
    _Pragma("unroll") for (int r = 0; r < 4; r++) {                                 \
      float p0 = __builtin_amdgcn_exp2f(sc0[r] - 8.0f);                             \
      float p1 = __builtin_amdgcn_exp2f(sc1[r] - 8.0f);                             \
      sc0[r] = p0; sc1[r] = p1; ls0 += p0; ls1 += p1;                               \
    }                                                                               \
    s16x4 P0 = { (short)f2bf(sc0[0]), (short)f2bf(sc0[1]),                          \
                 (short)f2bf(sc0[2]), (short)f2bf(sc0[3]) };                        \
    s16x4 P1 = { (short)f2bf(sc1[0]), (short)f2bf(sc1[1]),                          \
                 (short)f2bf(sc1[2]), (short)f2bf(sc1[3]) };                        \
    _Pragma("unroll") for (int dt = 0; dt < 8; dt++) {                              \
      O0[dt] = mfma16_bf16(VX[dt], P0, O0[dt]);                                     \
      O1[dt] = mfma16_bf16(VX[dt], P1, O1[dt]);                                     \
    }                                                                               \
  } while (0)

  if (nt > 0) LOADKV(KA, VA, 0);
  for (int j = 0; j < nt; j += 2) {
    if (j + 1 < nt) LOADKV(KB, VB, j + 1);
    COMPUTE(KA, VA, j);
    if (j + 2 < nt) LOADKV(KA, VA, j + 2);
    if (j + 1 < nt) COMPUTE(KB, VB, j + 1);
  }
#undef LOADKV
#undef COMPUTE

  // wave-level l reduce (sum over lk groups; k-additive so order-free)
  ls0 += __shfl_xor(ls0, 16); ls0 += __shfl_xor(ls0, 32);
  ls1 += __shfl_xor(ls1, 16); ls1 += __shfl_xor(ls1, 32);

  __syncthreads();
  if (wk == 1) {
#pragma unroll
    for (int dt = 0; dt < 8; dt++) {
      *(f32x4*)&eO[wq][dt][l][0] = O0[dt];
      *(f32x4*)&eO[wq][8 + dt][l][0] = O1[dt];
    }
    if (lk == 0) { eL[wq][0][lr] = ls0; eL[wq][1][lr] = ls1; }
  }
  __syncthreads();
  if (wk == 0) {
    const float inv0 = 1.0f / (ls0 + eL[wq][0][lr]);
    const float inv1 = 1.0f / (ls1 + eL[wq][1][lr]);
#pragma unroll
    for (int dt = 0; dt < 8; dt++) {
      f32x4 o0 = O0[dt] + *(const f32x4*)&eO[wq][dt][l][0];
      f32x4 o1 = O1[dt] + *(const f32x4*)&eO[wq][8 + dt][l][0];
      us4 s0 = { f2bf(o0[0] * inv0), f2bf(o0[1] * inv0), f2bf(o0[2] * inv0), f2bf(o0[3] * inv0) };
      us4 s1 = { f2bf(o1[0] * inv1), f2bf(o1[1] * inv1), f2bf(o1[2] * inv1), f2bf(o1[3] * inv1) };
      *(us4*)&ctx[(size_t)(qgb + lr) * D_MODEL + h * HD + dt * 16 + lk * 4] = s0;
      *(us4*)&ctx[(size_t)(qgb + 16 + lr) * D_MODEL + h * HD + dt * 16 + lk * 4] = s1;
    }
  }
}

extern "C" void kernel_launch(void* const* d_in, const int* in_sizes, int n_in,
                              void* d_out, int out_size, void* d_ws, size_t ws_size,
                              hipStream_t stream) {
  const float* x  = (const float*)d_in[0];
  const float* Wq = (const float*)d_in[1];
  const float* Wk = (const float*)d_in[2];
  const float* Wv = (const float*)d_in[3];
  const float* Wo = (const float*)d_in[4];
  const float* bo = (const float*)d_in[5];
  float* out = (float*)d_out;

  // ws: 5 slots x 8 MB = 40 MB (proven safe).
  //   S0: xb(b0); later ctx1    S1: qb; later wot    S2: kb    S3: vtb    S4: ctx0
  // d_out scratch until gemm_out: wqkvt (24 MB) + xb(b1) (8.4 MB) = exact fit.
  unsigned short* ws = (unsigned short*)d_ws;
  unsigned short* S0 = ws;
  unsigned short* S1 = ws + 1 * 4194304;
  unsigned short* S2 = ws + 2 * 4194304;
  unsigned short* S3 = ws + 3 * 4194304;
  unsigned short* S4 = ws + 4 * 4194304;
  unsigned short* wqkvt = (unsigned short*)d_out;
  unsigned short* xb1   = wqkvt + 12582912;

  dim3 tb(32, 8);

  transpose_cast3<<<dim3(64, 64, 3), tb, 0, stream>>>(Wq, Wk, Wv, wqkvt);
  cast_bf16_2<<<8192, 256, 0, stream>>>(x, S0, xb1);

  for (int b = 0; b < 2; b++) {
    const unsigned short* xb = (b == 0) ? S0 : xb1;
    unsigned short* ctx = (b == 0) ? S4 : S0;

    gemm_qkv<<<dim3(48, 16), 256, 0, stream>>>(xb, wqkvt, S1, S2, S3);
    attn_kernel<<<dim3(512), 256, 0, stream>>>(S1, S2, S3, ctx);
  }

  transpose_cast<<<dim3(64, 64), tb, 0, stream>>>(Wo, S1);
  gemm_out<<<dim3(16, 32), 256, 0, stream>>>(S4, S0, S1, bo, out);
}

// Round 15
// 283.857 us; speedup vs baseline: 1.3335x; 1.3335x over previous
//
#include <hip/hip_runtime.h>

#define S_LEN 2048
#define D_MODEL 2048
#define NH 16
#define HD 128

typedef __attribute__((ext_vector_type(4))) float f32x4;
typedef __attribute__((ext_vector_type(8))) short short8;
typedef __attribute__((ext_vector_type(8))) __bf16 bf16x8;
typedef __attribute__((ext_vector_type(4))) unsigned short us4;

__device__ __forceinline__ unsigned short f2bf(float f) {
  unsigned int u = __builtin_bit_cast(unsigned int, f);
  return (unsigned short)((u + 0x7fffu + ((u >> 16) & 1u)) >> 16);
}

__device__ __forceinline__ f32x4 mfma_bf16(short8 a, short8 b, f32x4 c) {
  return __builtin_amdgcn_mfma_f32_16x16x32_bf16(
      __builtin_bit_cast(bf16x8, a), __builtin_bit_cast(bf16x8, b), c, 0, 0, 0);
}

__device__ __forceinline__ void gload16(const unsigned short* g, unsigned short* l) {
  __builtin_amdgcn_global_load_lds(
      (const __attribute__((address_space(1))) void*)g,
      (__attribute__((address_space(3))) void*)l, 16, 0, 0);
}

// ---------------- cast x (f32 -> bf16), both batches in one dispatch ----------------
__global__ void cast_bf16_2(const float* __restrict__ src, unsigned short* __restrict__ dst0,
                            unsigned short* __restrict__ dst1) {
  int i = blockIdx.x * blockDim.x + threadIdx.x;
  float4 v = ((const float4*)src)[i];
  us4 o = { f2bf(v.x), f2bf(v.y), f2bf(v.z), f2bf(v.w) };
  if (i < 1048576) ((us4*)dst0)[i] = o;
  else             ((us4*)dst1)[i - 1048576] = o;
}

// ---------------- transpose-cast weights ----------------
__global__ void transpose_cast3(const float* __restrict__ Wq, const float* __restrict__ Wk,
                                const float* __restrict__ Wv, unsigned short* __restrict__ Wt) {
  __shared__ unsigned short tile[32][33];
  const float* W = (blockIdx.z == 0) ? Wq : (blockIdx.z == 1) ? Wk : Wv;
  unsigned short* dst = Wt + (size_t)blockIdx.z * 4194304;
  int bx = blockIdx.x * 32, by = blockIdx.y * 32;
  int tx = threadIdx.x, ty = threadIdx.y;
#pragma unroll
  for (int i = 0; i < 32; i += 8)
    tile[ty + i][tx] = f2bf(W[(by + ty + i) * D_MODEL + bx + tx]);
  __syncthreads();
#pragma unroll
  for (int i = 0; i < 32; i += 8)
    dst[(bx + ty + i) * D_MODEL + by + tx] = tile[tx][ty + i];
}

__global__ void transpose_cast(const float* __restrict__ W, unsigned short* __restrict__ Wt) {
  __shared__ unsigned short tile[32][33];
  int bx = blockIdx.x * 32, by = blockIdx.y * 32;
  int tx = threadIdx.x, ty = threadIdx.y;
#pragma unroll
  for (int i = 0; i < 32; i += 8)
    tile[ty + i][tx] = f2bf(W[(by + ty + i) * D_MODEL + bx + tx]);
  __syncthreads();
#pragma unroll
  for (int i = 0; i < 32; i += 8)
    Wt[(bx + ty + i) * D_MODEL + by + tx] = tile[tx][ty + i];
}

// ================= 128x128 GEMM K-loop (r9 structure: 3 blocks/CU, 100% fill) =================
#define GEMM_KLOOP(Ag0, Ag1, Bg0, Bg1, acc, t, fu, wr, wc, lr)           \
  __shared__ unsigned short lA[3][128 * 32];                             \
  __shared__ unsigned short lB[3][128 * 32];                             \
  do {                                                                   \
    const int nt = D_MODEL >> 5;                                         \
    _Pragma("unroll") for (int i = 0; i < 2; i++) {                      \
      const int _k = i * 32;                                             \
      gload16(Ag0 + _k, lA[i] + t * 8);                                  \
      gload16(Ag1 + _k, lA[i] + 2048 + t * 8);                           \
      gload16(Bg0 + _k, lB[i] + t * 8);                                  \
      gload16(Bg1 + _k, lB[i] + 2048 + t * 8);                           \
    }                                                                    \
    int cur = 0;                                                         \
    for (int tk = 0; tk < nt; ++tk) {                                    \
      if (tk + 1 < nt) {                                                 \
        asm volatile("s_waitcnt vmcnt(4)" ::: "memory");                 \
      } else {                                                           \
        asm volatile("s_waitcnt vmcnt(0)" ::: "memory");                 \
      }                                                                  \
      __builtin_amdgcn_sched_barrier(0);                                 \
      __builtin_amdgcn_s_barrier();                                      \
      __builtin_amdgcn_sched_barrier(0);                                 \
      if (tk + 2 < nt) {                                                 \
        int nx2 = cur + 2;                                               \
        if (nx2 >= 3) nx2 -= 3;                                          \
        const int _k = (tk + 2) * 32;                                    \
        gload16(Ag0 + _k, lA[nx2] + t * 8);                              \
        gload16(Ag1 + _k, lA[nx2] + 2048 + t * 8);                       \
        gload16(Bg0 + _k, lB[nx2] + t * 8);                              \
        gload16(Bg1 + _k, lB[nx2] + 2048 + t * 8);                       \
      }                                                                  \
      const unsigned short* a = lA[cur];                                 \
      const unsigned short* b = lB[cur];                                 \
      short8 af[4], bf[4];                                               \
      _Pragma("unroll") for (int mi = 0; mi < 4; mi++)                   \
        af[mi] = *(const short8*)&a[(wr * 64 + mi * 16 + lr) * 32 + fu]; \
      _Pragma("unroll") for (int ni = 0; ni < 4; ni++)                   \
        bf[ni] = *(const short8*)&b[(wc * 64 + ni * 16 + lr) * 32 + fu]; \
      __builtin_amdgcn_s_setprio(1);                                     \
      _Pragma("unroll") for (int mi = 0; mi < 4; mi++)                   \
        _Pragma("unroll") for (int ni = 0; ni < 4; ni++)                 \
          acc[mi][ni] = mfma_bf16(af[mi], bf[ni], acc[mi][ni]);          \
      __builtin_amdgcn_s_setprio(0);                                     \
      cur = (cur == 2) ? 0 : cur + 1;                                    \
    }                                                                    \
  } while (0)

// ---------------- fused QKV GEMM: [2048,2048] @ [6144,2048]^T ----------------
__global__ __launch_bounds__(256, 2) void gemm_qkv(
    const unsigned short* __restrict__ A, const unsigned short* __restrict__ Bt,
    unsigned short* __restrict__ qb, unsigned short* __restrict__ kb,
    unsigned short* __restrict__ vtb) {
  const int t = threadIdx.x;
  const int l = t & 63, w = t >> 6;
  const int wr = w >> 1, wc = w & 1;
  const int lr = l & 15, lk = l >> 4;
  const int n0 = blockIdx.x * 128, m0 = blockIdx.y * 128;

  const int arow = t >> 2;
  const int au = ((t & 3) ^ ((arow >> 1) & 3)) * 8;
  const unsigned short* Ag0 = A + (size_t)(m0 + arow) * D_MODEL + au;
  const unsigned short* Ag1 = Ag0 + 64 * D_MODEL;
  const unsigned short* Bg0 = Bt + (size_t)(n0 + arow) * D_MODEL + au;
  const unsigned short* Bg1 = Bg0 + 64 * D_MODEL;
  const int fu = (lk ^ ((lr >> 1) & 3)) * 8;

  f32x4 acc[4][4] = {};
  GEMM_KLOOP(Ag0, Ag1, Bg0, Bg1, acc, t, fu, wr, wc, lr);

  if (n0 < 4096) {
    unsigned short* C = (n0 < 2048) ? qb : kb;
    const int nbase = n0 & 2047;
#pragma unroll
    for (int mi = 0; mi < 4; mi++) {
      int r0 = m0 + wr * 64 + mi * 16 + lk * 4;
#pragma unroll
      for (int ni = 0; ni < 4; ni++) {
        int c2 = nbase + wc * 64 + ni * 16 + lr;
#pragma unroll
        for (int r = 0; r < 4; r++)
          C[(size_t)(r0 + r) * D_MODEL + c2] = f2bf(acc[mi][ni][r]);
      }
    }
  } else {
    const int nb = n0 - 4096;
#pragma unroll
    for (int mi = 0; mi < 4; mi++) {
      int s = m0 + wr * 64 + mi * 16 + lk * 4;
#pragma unroll
      for (int ni = 0; ni < 4; ni++) {
        int n = nb + wc * 64 + ni * 16 + lr;
        int h = n >> 7, d = n & (HD - 1);
        us4 pk = { f2bf(acc[mi][ni][0]), f2bf(acc[mi][ni][1]),
                   f2bf(acc[mi][ni][2]), f2bf(acc[mi][ni][3]) };
        *(us4*)&vtb[((size_t)(h * HD + d)) * S_LEN + s] = pk;
      }
    }
  }
}

// ---------------- combined output GEMM: [4096,2048] @ [2048,2048]^T + bias ----------------
__global__ __launch_bounds__(256, 2) void gemm_out(
    const unsigned short* __restrict__ ctx0, const unsigned short* __restrict__ ctx1,
    const unsigned short* __restrict__ Bt, const float* __restrict__ bias,
    float* __restrict__ out) {
  const int t = threadIdx.x;
  const int l = t & 63, w = t >> 6;
  const int wr = w >> 1, wc = w & 1;
  const int lr = l & 15, lk = l >> 4;
  const int n0 = blockIdx.x * 128, m0 = blockIdx.y * 128;

  const unsigned short* Ablk = (m0 < 2048)
      ? ctx0 + (size_t)m0 * D_MODEL
      : ctx1 + (size_t)(m0 - 2048) * D_MODEL;

  const int arow = t >> 2;
  const int au = ((t & 3) ^ ((arow >> 1) & 3)) * 8;
  const unsigned short* Ag0 = Ablk + (size_t)arow * D_MODEL + au;
  const unsigned short* Ag1 = Ag0 + 64 * D_MODEL;
  const unsigned short* Bg0 = Bt + (size_t)(n0 + arow) * D_MODEL + au;
  const unsigned short* Bg1 = Bg0 + 64 * D_MODEL;
  const int fu = (lk ^ ((lr >> 1) & 3)) * 8;

  f32x4 acc[4][4] = {};
  GEMM_KLOOP(Ag0, Ag1, Bg0, Bg1, acc, t, fu, wr, wc, lr);

#pragma unroll
  for (int mi = 0; mi < 4; mi++) {
    int r0 = m0 + wr * 64 + mi * 16 + lk * 4;
#pragma unroll
    for (int ni = 0; ni < 4; ni++) {
      int c2 = n0 + wc * 64 + ni * 16 + lr;
      float bv = bias[c2];
#pragma unroll
      for (int r = 0; r < 4; r++)
        out[(size_t)(r0 + r) * D_MODEL + c2] = acc[mi][ni][r] + bv;
    }
  }
}

// ---------------- flash attention (causal), per-batch ----------------
// r12 (passed full screen at 283.97 us): depth-2 staging pipeline. Stage tile t+2
// at END of iter t (second barrier guarantees buf(par) no longer read); gate with
// counted vmcnt(8); tail falls back to vmcnt(0). Fixed-base softmax (M0=8, log2
// domain, exact power-of-2 shift), swapped QK^T, K+V double-buffered, P wave-
// private in LDS.
__global__ __launch_bounds__(256, 2) void attn_kernel(
    const unsigned short* __restrict__ Q, const unsigned short* __restrict__ K,
    const unsigned short* __restrict__ Vt, unsigned short* __restrict__ ctx) {
  __shared__ unsigned short lds[36864];  // 72 KB: K dbuf 2x16KB + V dbuf 2x16KB + P 8KB

  const int id = blockIdx.x;
  const int h = id & 15;
  const int qtl = id >> 4;
  const int qt = (qtl < 16) ? (2 * qtl) : (63 - 2 * qtl);

  const int t = threadIdx.x, l = t & 63, w = t >> 6;
  const int lr = l & 15, lk = l >> 4;

  const float qscale = 0.08838834764831845f * 1.44269504088896340f;
  const unsigned short* qsrc = Q + (size_t)(qt * 64 + w * 16 + lr) * D_MODEL + h * HD;
  short8 Qf[4];
#pragma unroll
  for (int kk = 0; kk < 4; kk++) {
    short8 qv = *(const short8*)&qsrc[kk * 32 + lk * 8];
#pragma unroll
    for (int e = 0; e < 8; e++) {
      unsigned int u = ((unsigned int)(unsigned short)qv[e]) << 16;
      float f = __builtin_bit_cast(float, u) * qscale;
      qv[e] = (short)f2bf(f);
    }
    Qf[kk] = qv;
  }

  const unsigned short* ksrc = K + h * HD;
  const unsigned short* vsrc = Vt + (size_t)h * HD * S_LEN;
  const int krow = t >> 4, kcs = t & 15;
  const int vrow = t >> 3, vcs = t & 7;

#define STAGE_KV(par, kv0base)                                                    \
  do {                                                                            \
    unsigned short* lKb = lds + (par) * 8192;                                     \
    unsigned short* lVb = lds + 16384 + (par) * 8192;                             \
    _Pragma("unroll") for (int i = 0; i < 4; i++) {                               \
      int row = i * 16 + krow;                                                    \
      gload16(ksrc + (size_t)((kv0base) + row) * D_MODEL + ((kcs ^ (row & 7)) * 8), \
              lKb + row * 128 + kcs * 8);                                         \
    }                                                                             \
    _Pragma("unroll") for (int i = 0; i < 4; i++) {                               \
      int row = i * 32 + vrow;                                                    \
      gload16(vsrc + (size_t)row * S_LEN + (kv0base) + ((vcs ^ (row & 7)) * 8),   \
              lVb + row * 64 + vcs * 8);                                          \
    }                                                                             \
  } while (0)

  f32x4 O[8] = {};
  float l_s = 0.f;
  const float M0 = 8.0f;
  const int nkv = qt + 1;
  unsigned short* lPw = lds + 32768 + w * 1024;

  // prologue: stage tiles 0 and 1 (depth 2)
  STAGE_KV(0, 0);
  if (nkv > 1) STAGE_KV(1, 64);

  for (int tk = 0; tk < nkv; tk++) {
    const int kv0 = tk * 64;
    const int par = tk & 1;
    const unsigned short* lKc = lds + par * 8192;
    const unsigned short* lVc = lds + 16384 + par * 8192;

    // gate: tile tk's 8 loads done; tile tk+1's (if staged) stay in flight
    if (tk + 1 < nkv) {
      asm volatile("s_waitcnt vmcnt(8)" ::: "memory");
    } else {
      asm volatile("s_waitcnt vmcnt(0)" ::: "memory");
    }
    __builtin_amdgcn_sched_barrier(0);
    __builtin_amdgcn_s_barrier();
    __builtin_amdgcn_sched_barrier(0);

    f32x4 sc[4] = {};
    __builtin_amdgcn_s_setprio(1);
#pragma unroll
    for (int kk = 0; kk < 4; kk++) {
      short8 Kf[4];
#pragma unroll
      for (int ni = 0; ni < 4; ni++)
        Kf[ni] = *(const short8*)&lKc[(ni * 16 + lr) * 128 + (((kk * 4 + lk) ^ (lr & 7)) * 8)];
#pragma unroll
      for (int ni = 0; ni < 4; ni++)
        sc[ni] = mfma_bf16(Kf[ni], Qf[kk], sc[ni]);
    }
    __builtin_amdgcn_s_setprio(0);

    const int row0g = qt * 64 + w * 16 + lr;
    if (tk == qt) {
#pragma unroll
      for (int ni = 0; ni < 4; ni++) {
        const int colb = kv0 + ni * 16 + lk * 4;
#pragma unroll
        for (int r = 0; r < 4; r++)
          if (colb + r > row0g) sc[ni][r] = -1e30f;
      }
    }

    float rs = 0.f;
#pragma unroll
    for (int ni = 0; ni < 4; ni++)
#pragma unroll
      for (int r = 0; r < 4; r++) {
        float p = __builtin_amdgcn_exp2f(sc[ni][r] - M0);
        sc[ni][r] = p;
        rs += p;
      }
    rs += __shfl_xor(rs, 16);
    rs += __shfl_xor(rs, 32);
    l_s += rs;

#pragma unroll
    for (int ni = 0; ni < 4; ni++) {
      us4 pk = { f2bf(sc[ni][0]), f2bf(sc[ni][1]), f2bf(sc[ni][2]), f2bf(sc[ni][3]) };
      int u16 = (ni * 2 + (lk >> 1)) ^ (lr & 7);
      *(us4*)&lPw[lr * 64 + u16 * 8 + (lk & 1) * 4] = pk;
    }

    __builtin_amdgcn_s_setprio(1);
#pragma unroll
    for (int kk = 0; kk < 2; kk++) {
      short8 Pf = *(const short8*)&lPw[lr * 64 + (((kk * 4 + lk) ^ (lr & 7)) * 8)];
#pragma unroll
      for (int di = 0; di < 8; di++) {
        short8 Vf = *(const short8*)&lVc[(di * 16 + lr) * 64 + (((kk * 4 + lk) ^ (lr & 7)) * 8)];
        O[di] = mfma_bf16(Pf, Vf, O[di]);
      }
    }
    __builtin_amdgcn_s_setprio(0);

    // all waves done reading buf(par) before tile tk+2 overwrites it
    __builtin_amdgcn_s_barrier();
    __builtin_amdgcn_sched_barrier(0);
    if (tk + 2 < nkv) STAGE_KV(par, kv0 + 128);
  }
#undef STAGE_KV

  float lr4[4];
#pragma unroll
  for (int r = 0; r < 4; r++) lr4[r] = __shfl(l_s, lk * 4 + r);
#pragma unroll
  for (int di = 0; di < 8; di++)
#pragma unroll
    for (int r = 0; r < 4; r++) {
      float v = O[di][r] / lr4[r];
      ctx[(size_t)(qt * 64 + w * 16 + lk * 4 + r) * D_MODEL + h * HD + di * 16 + lr] = f2bf(v);
    }
}

extern "C" void kernel_launch(void* const* d_in, const int* in_sizes, int n_in,
                              void* d_out, int out_size, void* d_ws, size_t ws_size,
                              hipStream_t stream) {
  const float* x  = (const float*)d_in[0];
  const float* Wq = (const float*)d_in[1];
  const float* Wk = (const float*)d_in[2];
  const float* Wv = (const float*)d_in[3];
  const float* Wo = (const float*)d_in[4];
  const float* bo = (const float*)d_in[5];
  float* out = (float*)d_out;

  // ws: 5 slots x 8 MB = 40 MB (proven safe).
  //   S0: xb(b0); later ctx1    S1: qb; later wot    S2: kb    S3: vtb    S4: ctx0
  // d_out scratch until gemm_out: wqkvt (24 MB) + xb(b1) (8.4 MB) = exact fit.
  unsigned short* ws = (unsigned short*)d_ws;
  unsigned short* S0 = ws;
  unsigned short* S1 = ws + 1 * 4194304;
  unsigned short* S2 = ws + 2 * 4194304;
  unsigned short* S3 = ws + 3 * 4194304;
  unsigned short* S4 = ws + 4 * 4194304;
  unsigned short* wqkvt = (unsigned short*)d_out;
  unsigned short* xb1   = wqkvt + 12582912;

  dim3 tb(32, 8);

  transpose_cast3<<<dim3(64, 64, 3), tb, 0, stream>>>(Wq, Wk, Wv, wqkvt);
  cast_bf16_2<<<8192, 256, 0, stream>>>(x, S0, xb1);

  for (int b = 0; b < 2; b++) {
    const unsigned short* xb = (b == 0) ? S0 : xb1;
    unsigned short* ctx = (b == 0) ? S4 : S0;

    gemm_qkv<<<dim3(48, 16), 256, 0, stream>>>(xb, wqkvt, S1, S2, S3);
    attn_kernel<<<dim3(512), 256, 0, stream>>>(S1, S2, S3, ctx);
  }

  transpose_cast<<<dim3(64, 64), tb, 0, stream>>>(Wo, S1);
  gemm_out<<<dim3(16, 32), 256, 0, stream>>>(S4, S0, S1, bo, out);
}